// Round 1
// baseline (325.361 us; speedup 1.0000x reference)
//
#include <hip/hip_runtime.h>

typedef _Float16 f16;
typedef _Float16 f16x4 __attribute__((ext_vector_type(4)));
typedef _Float16 f16x8 __attribute__((ext_vector_type(8)));
typedef float f32x4 __attribute__((ext_vector_type(4)));

#define L_SEQ 4096
#define D_MODEL 512
#define D_HEAD 64

__device__ __forceinline__ void gload16(const void* g, void* l) {
  __builtin_amdgcn_global_load_lds((const __attribute__((address_space(1))) void*)g,
                                   (__attribute__((address_space(3))) void*)l, 16, 0, 0);
}

// ---------------- f32 -> f16 elementwise (vec4) ----------------
__global__ void cvt_f16_kernel(const float* __restrict__ s, f16* __restrict__ d, int n4) {
  int i = blockIdx.x * blockDim.x + threadIdx.x;
  if (i >= n4) return;
  float4 v = ((const float4*)s)[i];
  f16x4 o;
  o[0] = (f16)v.x; o[1] = (f16)v.y; o[2] = (f16)v.z; o[3] = (f16)v.w;
  ((f16x4*)d)[i] = o;
}

// ---------------- 512x512 f32 -> transposed f16 (7 matrices) ----------------
__global__ void transpose7_kernel(
    const float* __restrict__ s0, const float* __restrict__ s1, const float* __restrict__ s2,
    const float* __restrict__ s3, const float* __restrict__ s4, const float* __restrict__ s5,
    const float* __restrict__ s6,
    f16* __restrict__ d0, f16* __restrict__ d1, f16* __restrict__ d2,
    f16* __restrict__ d3, f16* __restrict__ d4, f16* __restrict__ d5,
    f16* __restrict__ d6)
{
  const float* s; f16* d;
  switch (blockIdx.z) {
    case 0: s = s0; d = d0; break;
    case 1: s = s1; d = d1; break;
    case 2: s = s2; d = d2; break;
    case 3: s = s3; d = d3; break;
    case 4: s = s4; d = d4; break;
    case 5: s = s5; d = d5; break;
    default: s = s6; d = d6; break;
  }
  __shared__ float tl[32][33];
  const int bx = blockIdx.x * 32, by = blockIdx.y * 32;
  const int tx = threadIdx.x, ty = threadIdx.y;
  #pragma unroll
  for (int i = 0; i < 4; ++i)
    tl[ty + i * 8][tx] = s[(size_t)(by + ty + i * 8) * 512 + bx + tx];
  __syncthreads();
  #pragma unroll
  for (int i = 0; i < 4; ++i)
    d[(size_t)(bx + ty + i * 8) * 512 + by + tx] = (f16)tl[tx][ty + i * 8];
}

// ---------------- GEMM: C[M,N] = A[M,K] @ B[K,N] + bias, B given transposed [N,K] ----------------
// MODE 0: f16 row-major out; MODE 1: f16 transposed out [N,M]; MODE 2: f32 row-major out
template<int MODE>
__global__ __launch_bounds__(256) void gemm_bt_kernel(
    const f16* __restrict__ A, const f16* __restrict__ BT,
    const float* __restrict__ bias, void* __restrict__ Cv,
    int M, int N, int K)
{
  __shared__ __attribute__((aligned(16))) f16 As[128 * 32];
  __shared__ __attribute__((aligned(16))) f16 Bs[64 * 32];
  const int t = threadIdx.x;
  const int w = t >> 6;
  const int bm = blockIdx.x * 128, bn = blockIdx.y * 64;
  const int m0 = (w >> 1) * 64, n0 = (w & 1) * 32;
  const int lane = t & 63, lr = lane & 15, lg = lane >> 4;

  f32x4 zf = {0.f, 0.f, 0.f, 0.f};
  f32x4 acc[4][2];
  #pragma unroll
  for (int i = 0; i < 4; ++i)
    #pragma unroll
    for (int j = 0; j < 2; ++j)
      acc[i][j] = zf;

  const int arow = t >> 2, achk = t & 3;
  const f16* gA = A + (size_t)(bm + arow) * K + achk * 8;
  const f16* gB = BT + (size_t)(bn + arow) * K + achk * 8;
  f16* lA = As + w * 512;   // HW adds lane*16B
  f16* lB = Bs + w * 512;

  for (int k0 = 0; k0 < K; k0 += 32) {
    gload16(gA + k0, lA);
    gload16(gA + (size_t)64 * K + k0, lA + 2048);
    gload16(gB + k0, lB);
    __syncthreads();   // drains vmcnt -> LDS valid
    f16x8 af[4], bfv[2];
    #pragma unroll
    for (int i = 0; i < 4; ++i)
      af[i] = *(const f16x8*)&As[(m0 + i * 16 + lr) * 32 + lg * 8];
    #pragma unroll
    for (int j = 0; j < 2; ++j)
      bfv[j] = *(const f16x8*)&Bs[(n0 + j * 16 + lr) * 32 + lg * 8];
    #pragma unroll
    for (int i = 0; i < 4; ++i)
      #pragma unroll
      for (int j = 0; j < 2; ++j)
        acc[i][j] = __builtin_amdgcn_mfma_f32_16x16x32_f16(af[i], bfv[j], acc[i][j], 0, 0, 0);
    __syncthreads();   // all waves done reading before next stage
  }

  #pragma unroll
  for (int j = 0; j < 2; ++j) {
    const int gn = bn + n0 + j * 16 + lr;
    const float bv = bias[gn];
    #pragma unroll
    for (int i = 0; i < 4; ++i) {
      const int gmb = bm + m0 + i * 16 + lg * 4;
      if constexpr (MODE == 0) {
        f16* C = (f16*)Cv;
        #pragma unroll
        for (int r = 0; r < 4; ++r)
          C[(size_t)(gmb + r) * N + gn] = (f16)(acc[i][j][r] + bv);
      } else if constexpr (MODE == 1) {
        f16* C = (f16*)Cv;   // [N, M]
        f16x4 u;
        u[0] = (f16)(acc[i][j][0] + bv);
        u[1] = (f16)(acc[i][j][1] + bv);
        u[2] = (f16)(acc[i][j][2] + bv);
        u[3] = (f16)(acc[i][j][3] + bv);
        *(f16x4*)&C[(size_t)gn * M + gmb] = u;
      } else {
        float* C = (float*)Cv;
        #pragma unroll
        for (int r = 0; r < 4; ++r)
          C[(size_t)(gmb + r) * N + gn] = acc[i][j][r] + bv;
      }
    }
  }
}

// ---------------- fused attention ----------------
// grid = 256 blocks (16 q-rows each), 512 threads = 8 waves, wave w == head w.
// sp row-softmax computed into LDS once per block (exp values f16 + per-row scale),
// shared across all 8 heads. No max-subtraction needed: logits are O(1).
__global__ __launch_bounds__(512) void attn_kernel(
    const f16* __restrict__ qg, const f16* __restrict__ kg,
    const f16* __restrict__ vTg, const float* __restrict__ spg,
    f16* __restrict__ og)
{
  __shared__ __attribute__((aligned(16))) f16 sp_lds[16 * 4100];  // pad 4 -> row stride 8200B
  __shared__ __attribute__((aligned(16))) f16 p_lds[8 * 640];     // per-wave 16x32, row stride 40
  __shared__ float scale_lds[16];

  const int t = threadIdx.x;
  const int q0 = blockIdx.x * 16;

  // --- stage 1: sp = softmax(shortest_path rows); store exp(x) f16 + 0.5/rowsum ---
  {
    const int row = t >> 5, j = t & 31;
    const float4* srow = (const float4*)(spg + (size_t)(q0 + row) * L_SEQ);
    f16* dst = sp_lds + row * 4100;
    float ssum = 0.f;
    for (int c = 0; c < 32; ++c) {
      float4 v = srow[c * 32 + j];
      float e0 = __expf(v.x), e1 = __expf(v.y), e2 = __expf(v.z), e3 = __expf(v.w);
      ssum += (e0 + e1) + (e2 + e3);
      f16x4 u;
      u[0] = (f16)e0; u[1] = (f16)e1; u[2] = (f16)e2; u[3] = (f16)e3;
      *(f16x4*)&dst[(c * 32 + j) * 4] = u;
    }
    ssum += __shfl_xor(ssum, 1, 64);
    ssum += __shfl_xor(ssum, 2, 64);
    ssum += __shfl_xor(ssum, 4, 64);
    ssum += __shfl_xor(ssum, 8, 64);
    ssum += __shfl_xor(ssum, 16, 64);
    if (j == 0) scale_lds[row] = 0.5f / ssum;
  }
  __syncthreads();

  const int h = t >> 6;                 // head = wave id
  const int lane = t & 63, lr = lane & 15, lg = lane >> 4;

  f16x8 qf0, qf1;
  {
    const f16* qp = qg + (size_t)(q0 + lr) * D_MODEL + h * D_HEAD + lg * 8;
    qf0 = *(const f16x8*)qp;
    qf1 = *(const f16x8*)(qp + 32);
  }
  float rsc[4];
  #pragma unroll
  for (int r = 0; r < 4; ++r) rsc[r] = scale_lds[lg * 4 + r];

  f32x4 zf = {0.f, 0.f, 0.f, 0.f};
  f32x4 o[4];
  #pragma unroll
  for (int dg = 0; dg < 4; ++dg) o[dg] = zf;
  float rs[4] = {0.f, 0.f, 0.f, 0.f};

  f16* myp = p_lds + h * 640;

  for (int kv0 = 0; kv0 < L_SEQ; kv0 += 32) {
    // S = Q @ K^T  (two 16-col fragments)
    f32x4 s0 = zf, s1 = zf;
    {
      const f16* kp = kg + (size_t)(kv0 + lr) * D_MODEL + h * D_HEAD + lg * 8;
      f16x8 ka = *(const f16x8*)kp;
      f16x8 kb = *(const f16x8*)(kp + 32);
      s0 = __builtin_amdgcn_mfma_f32_16x16x32_f16(qf0, ka, s0, 0, 0, 0);
      s0 = __builtin_amdgcn_mfma_f32_16x16x32_f16(qf1, kb, s0, 0, 0, 0);
      const f16* kp2 = kp + (size_t)16 * D_MODEL;
      f16x8 kc = *(const f16x8*)kp2;
      f16x8 kd = *(const f16x8*)(kp2 + 32);
      s1 = __builtin_amdgcn_mfma_f32_16x16x32_f16(qf0, kc, s1, 0, 0, 0);
      s1 = __builtin_amdgcn_mfma_f32_16x16x32_f16(qf1, kd, s1, 0, 0, 0);
    }
    // p = exp(S/8 + sp)  (no max shift needed; logits O(1))
    #pragma unroll
    for (int r = 0; r < 4; ++r) {
      const int srow = lg * 4 + r;
      float e0 = (float)sp_lds[srow * 4100 + kv0 + lr];
      float e1 = (float)sp_lds[srow * 4100 + kv0 + 16 + lr];
      float p0 = __expf(fmaf(s0[r], 0.125f, e0 * rsc[r]));
      float p1 = __expf(fmaf(s1[r], 0.125f, e1 * rsc[r]));
      rs[r] += p0 + p1;
      myp[srow * 40 + lr] = (f16)p0;
      myp[srow * 40 + 16 + lr] = (f16)p1;
    }
    // P (A-layout via LDS) @ V
    f16x8 pf = *(const f16x8*)&myp[lr * 40 + lg * 8];
    #pragma unroll
    for (int dg = 0; dg < 4; ++dg) {
      const f16* vp = vTg + (size_t)(h * D_HEAD + dg * 16 + lr) * L_SEQ + kv0 + lg * 8;
      f16x8 vf = *(const f16x8*)vp;
      o[dg] = __builtin_amdgcn_mfma_f32_16x16x32_f16(pf, vf, o[dg], 0, 0, 0);
    }
  }

  // row-sum reduce across the 16 col-lanes, then normalize
  #pragma unroll
  for (int r = 0; r < 4; ++r) {
    float v = rs[r];
    v += __shfl_xor(v, 1, 64);
    v += __shfl_xor(v, 2, 64);
    v += __shfl_xor(v, 4, 64);
    v += __shfl_xor(v, 8, 64);
    rs[r] = 1.f / v;
  }
  #pragma unroll
  for (int dg = 0; dg < 4; ++dg)
    #pragma unroll
    for (int r = 0; r < 4; ++r)
      og[(size_t)(q0 + lg * 4 + r) * D_MODEL + h * D_HEAD + dg * 16 + lr] =
          (f16)(o[dg][r] * rs[r]);
}

// ---------------- host ----------------
extern "C" void kernel_launch(void* const* d_in, const int* in_sizes, int n_in,
                              void* d_out, int out_size, void* d_ws, size_t ws_size,
                              hipStream_t stream)
{
  (void)in_sizes; (void)n_in; (void)out_size; (void)ws_size;

  const float* x    = (const float*)d_in[0];
  const float* sp   = (const float*)d_in[1];
  const float* wq_w = (const float*)d_in[2];
  const float* wq_b = (const float*)d_in[3];
  const float* wk_w = (const float*)d_in[4];
  const float* wk_b = (const float*)d_in[5];
  const float* wv_w = (const float*)d_in[6];
  const float* wv_b = (const float*)d_in[7];
  const float* qp_w = (const float*)d_in[8];
  const float* qp_b = (const float*)d_in[9];
  const float* kp_w = (const float*)d_in[10];
  const float* kp_b = (const float*)d_in[11];
  const float* vp_w = (const float*)d_in[12];
  const float* vp_b = (const float*)d_in[13];
  const float* out_w = (const float*)d_in[14];
  const float* out_b = (const float*)d_in[15];

  char* ws = (char*)d_ws;
  f16* x_f   = (f16*)(ws + (size_t)0);          // 4 MiB
  f16* wT    = (f16*)(ws + (size_t)4194304);    // 7 x 512 KiB
  f16* tmp   = (f16*)(ws + (size_t)7864320);    // 4 MiB
  f16* q_f   = (f16*)(ws + (size_t)12058624);
  f16* k_f   = (f16*)(ws + (size_t)16252928);
  f16* vT    = (f16*)(ws + (size_t)20447232);
  f16* attout= (f16*)(ws + (size_t)24641536);

  f16* wqT  = wT + (size_t)0 * 262144;
  f16* wkT  = wT + (size_t)1 * 262144;
  f16* wvT  = wT + (size_t)2 * 262144;
  f16* qpT  = wT + (size_t)3 * 262144;
  f16* kpT  = wT + (size_t)4 * 262144;
  f16* vpT  = wT + (size_t)5 * 262144;
  f16* outT = wT + (size_t)6 * 262144;

  cvt_f16_kernel<<<2048, 256, 0, stream>>>(x, x_f, 524288);
  transpose7_kernel<<<dim3(16, 16, 7), dim3(32, 8), 0, stream>>>(
      wq_w, wk_w, wv_w, qp_w, kp_w, vp_w, out_w,
      wqT,  wkT,  wvT,  qpT,  kpT,  vpT,  outT);

  dim3 gg(32, 8);
  gemm_bt_kernel<0><<<gg, 256, 0, stream>>>(x_f, wqT, wq_b, tmp,  4096, 512, 512);
  gemm_bt_kernel<0><<<gg, 256, 0, stream>>>(tmp, qpT, qp_b, q_f,  4096, 512, 512);
  gemm_bt_kernel<0><<<gg, 256, 0, stream>>>(x_f, wkT, wk_b, tmp,  4096, 512, 512);
  gemm_bt_kernel<0><<<gg, 256, 0, stream>>>(tmp, kpT, kp_b, k_f,  4096, 512, 512);
  gemm_bt_kernel<0><<<gg, 256, 0, stream>>>(x_f, wvT, wv_b, tmp,  4096, 512, 512);
  gemm_bt_kernel<1><<<gg, 256, 0, stream>>>(tmp, vpT, vp_b, vT,   4096, 512, 512);

  attn_kernel<<<256, 512, 0, stream>>>(q_f, k_f, vT, sp, attout);

  gemm_bt_kernel<2><<<gg, 256, 0, stream>>>(attout, outT, out_b, d_out, 4096, 512, 512);
}

// Round 2
// 186.229 us; speedup vs baseline: 1.7471x; 1.7471x over previous
//
#include <hip/hip_runtime.h>

typedef _Float16 f16;
typedef _Float16 f16x4 __attribute__((ext_vector_type(4)));
typedef _Float16 f16x8 __attribute__((ext_vector_type(8)));
typedef float f32x4 __attribute__((ext_vector_type(4)));

#define L_SEQ 4096
#define D_MODEL 512
#define D_HEAD 64
#define KVSPLIT 2

__device__ __forceinline__ void gload16(const void* g, void* l) {
  __builtin_amdgcn_global_load_lds((const __attribute__((address_space(1))) void*)g,
                                   (__attribute__((address_space(3))) void*)l, 16, 0, 0);
}

// ---------------- f32 -> f16 elementwise (vec4) ----------------
__global__ void cvt_f16_kernel(const float* __restrict__ s, f16* __restrict__ d, int n4) {
  int i = blockIdx.x * blockDim.x + threadIdx.x;
  if (i >= n4) return;
  float4 v = ((const float4*)s)[i];
  f16x4 o;
  o[0] = (f16)v.x; o[1] = (f16)v.y; o[2] = (f16)v.z; o[3] = (f16)v.w;
  ((f16x4*)d)[i] = o;
}

// ---------------- 512x512 f32 -> transposed f16 (7 matrices) ----------------
__global__ void transpose7_kernel(
    const float* __restrict__ s0, const float* __restrict__ s1, const float* __restrict__ s2,
    const float* __restrict__ s3, const float* __restrict__ s4, const float* __restrict__ s5,
    const float* __restrict__ s6,
    f16* __restrict__ d0, f16* __restrict__ d1, f16* __restrict__ d2,
    f16* __restrict__ d3, f16* __restrict__ d4, f16* __restrict__ d5,
    f16* __restrict__ d6)
{
  const float* s; f16* d;
  switch (blockIdx.z) {
    case 0: s = s0; d = d0; break;
    case 1: s = s1; d = d1; break;
    case 2: s = s2; d = d2; break;
    case 3: s = s3; d = d3; break;
    case 4: s = s4; d = d4; break;
    case 5: s = s5; d = d5; break;
    default: s = s6; d = d6; break;
  }
  __shared__ float tl[32][33];
  const int bx = blockIdx.x * 32, by = blockIdx.y * 32;
  const int tx = threadIdx.x, ty = threadIdx.y;
  #pragma unroll
  for (int i = 0; i < 4; ++i)
    tl[ty + i * 8][tx] = s[(size_t)(by + ty + i * 8) * 512 + bx + tx];
  __syncthreads();
  #pragma unroll
  for (int i = 0; i < 4; ++i)
    d[(size_t)(bx + ty + i * 8) * 512 + by + tx] = (f16)tl[tx][ty + i * 8];
}

// ---------------- GEMM: C[M,N] = A[M,K] @ B[K,N] + bias, B given transposed [N,K] ----------------
template<int MODE>
__global__ __launch_bounds__(256) void gemm_bt_kernel(
    const f16* __restrict__ A, const f16* __restrict__ BT,
    const float* __restrict__ bias, void* __restrict__ Cv,
    int M, int N, int K)
{
  __shared__ __attribute__((aligned(16))) f16 As[128 * 32];
  __shared__ __attribute__((aligned(16))) f16 Bs[64 * 32];
  const int t = threadIdx.x;
  const int w = t >> 6;
  const int bm = blockIdx.x * 128, bn = blockIdx.y * 64;
  const int m0 = (w >> 1) * 64, n0 = (w & 1) * 32;
  const int lane = t & 63, lr = lane & 15, lg = lane >> 4;

  f32x4 zf = {0.f, 0.f, 0.f, 0.f};
  f32x4 acc[4][2];
  #pragma unroll
  for (int i = 0; i < 4; ++i)
    #pragma unroll
    for (int j = 0; j < 2; ++j)
      acc[i][j] = zf;

  const int arow = t >> 2, achk = t & 3;
  const f16* gA = A + (size_t)(bm + arow) * K + achk * 8;
  const f16* gB = BT + (size_t)(bn + arow) * K + achk * 8;
  f16* lA = As + w * 512;
  f16* lB = Bs + w * 512;

  for (int k0 = 0; k0 < K; k0 += 32) {
    gload16(gA + k0, lA);
    gload16(gA + (size_t)64 * K + k0, lA + 2048);
    gload16(gB + k0, lB);
    __syncthreads();
    f16x8 af[4], bfv[2];
    #pragma unroll
    for (int i = 0; i < 4; ++i)
      af[i] = *(const f16x8*)&As[(m0 + i * 16 + lr) * 32 + lg * 8];
    #pragma unroll
    for (int j = 0; j < 2; ++j)
      bfv[j] = *(const f16x8*)&Bs[(n0 + j * 16 + lr) * 32 + lg * 8];
    #pragma unroll
    for (int i = 0; i < 4; ++i)
      #pragma unroll
      for (int j = 0; j < 2; ++j)
        acc[i][j] = __builtin_amdgcn_mfma_f32_16x16x32_f16(af[i], bfv[j], acc[i][j], 0, 0, 0);
    __syncthreads();
  }

  #pragma unroll
  for (int j = 0; j < 2; ++j) {
    const int gn = bn + n0 + j * 16 + lr;
    const float bv = bias[gn];
    #pragma unroll
    for (int i = 0; i < 4; ++i) {
      const int gmb = bm + m0 + i * 16 + lg * 4;
      if constexpr (MODE == 0) {
        f16* C = (f16*)Cv;
        #pragma unroll
        for (int r = 0; r < 4; ++r)
          C[(size_t)(gmb + r) * N + gn] = (f16)(acc[i][j][r] + bv);
      } else if constexpr (MODE == 1) {
        f16* C = (f16*)Cv;   // [N, M]
        f16x4 u;
        u[0] = (f16)(acc[i][j][0] + bv);
        u[1] = (f16)(acc[i][j][1] + bv);
        u[2] = (f16)(acc[i][j][2] + bv);
        u[3] = (f16)(acc[i][j][3] + bv);
        *(f16x4*)&C[(size_t)gn * M + gmb] = u;
      } else {
        float* C = (float*)Cv;
        #pragma unroll
        for (int r = 0; r < 4; ++r)
          C[(size_t)(gmb + r) * N + gn] = acc[i][j][r] + bv;
      }
    }
  }
}

// ---------------- sp bias precompute ----------------
// bias = 0.5*softmax(sp, axis=-1), written f16 in MFMA-fragment tile order:
// bt[(q>>4)*65536 + (kv>>4)*256 + (kv&15)*16 + ((q>>2)&3)*4 + (q&3)]
__global__ __launch_bounds__(512) void sp_bias_kernel(
    const float* __restrict__ spg, f16* __restrict__ bt)
{
  __shared__ __attribute__((aligned(16))) f16 ex[16 * 4100];
  __shared__ float sums[16];
  const int t = threadIdx.x;

  {
    const int row = t >> 5, j = t & 31;
    const float4* srow = (const float4*)(spg + (size_t)(blockIdx.x * 16 + row) * L_SEQ);
    f16* dst = ex + row * 4100;
    float ssum = 0.f;
    #pragma unroll 4
    for (int c = 0; c < 32; ++c) {
      float4 v = srow[c * 32 + j];
      float e0 = __expf(v.x), e1 = __expf(v.y), e2 = __expf(v.z), e3 = __expf(v.w);
      ssum += (e0 + e1) + (e2 + e3);
      f16x4 u;
      u[0] = (f16)e0; u[1] = (f16)e1; u[2] = (f16)e2; u[3] = (f16)e3;
      *(f16x4*)&dst[(c * 32 + j) * 4] = u;
    }
    ssum += __shfl_xor(ssum, 1, 64);
    ssum += __shfl_xor(ssum, 2, 64);
    ssum += __shfl_xor(ssum, 4, 64);
    ssum += __shfl_xor(ssum, 8, 64);
    ssum += __shfl_xor(ssum, 16, 64);
    if (j == 0) sums[row] = ssum;
  }
  __syncthreads();

  const int w = t >> 6, lane = t & 63, lr = lane & 15, lg = lane >> 4;
  float rsc[4];
  #pragma unroll
  for (int r = 0; r < 4; ++r) rsc[r] = 0.5f / sums[lg * 4 + r];

  f16* obase = bt + (size_t)blockIdx.x * 65536 + lr * 16 + lg * 4;
  #pragma unroll 4
  for (int i = 0; i < 32; ++i) {
    const int tt = w + i * 8;
    f16x4 u;
    #pragma unroll
    for (int r = 0; r < 4; ++r)
      u[r] = (f16)((float)ex[(lg * 4 + r) * 4100 + tt * 16 + lr] * rsc[r]);
    *(f16x4*)&obase[tt * 256] = u;
  }
}

// ---------------- fused attention (kv-split partials) ----------------
// grid dim3(8, 32, KVSPLIT): x=head (-> XCD), y=q-tile(128), z=kv-split.
// block 256 thr = 4 waves; wave owns 32 q-rows. K/V double-buffered LDS.
__global__ __launch_bounds__(256, 2) void attn2_kernel(
    const f16* __restrict__ qg, const f16* __restrict__ kg,
    const f16* __restrict__ vTg, const f16* __restrict__ bt,
    float* __restrict__ opart, float* __restrict__ rspart)
{
  // [buf][dh*2048 + row*32 + c] rows=kv, c=d-within-half
  __shared__ __attribute__((aligned(16))) f16 Ks[2][4096];
  // [buf][kh*2048 + row*32 + c] rows=d, c=kv-within-half
  __shared__ __attribute__((aligned(16))) f16 Vs[2][4096];
  // per-wave P: [kh*1280 + q*40 + c]
  __shared__ __attribute__((aligned(16))) f16 Ps[4][2560];

  const int t = threadIdx.x;
  const int w = t >> 6, lane = t & 63, lr = lane & 15, lg = lane >> 4;
  const int h = blockIdx.x;
  const int q0 = blockIdx.y * 128 + w * 32;
  const int kvbase = blockIdx.z * (L_SEQ / KVSPLIT);
  const int nsteps = (L_SEQ / KVSPLIT) / 64;

  // Q fragments (persist)
  f16x8 qf[2][2];
  #pragma unroll
  for (int sub = 0; sub < 2; ++sub)
    #pragma unroll
    for (int dh = 0; dh < 2; ++dh)
      qf[sub][dh] = *(const f16x8*)&qg[(size_t)(q0 + sub * 16 + lr) * D_MODEL +
                                       h * D_HEAD + dh * 32 + lg * 8];

  const int r0 = w * 2, r1 = w * 2 + 1;
  const int krow0 = (r0 & 3) * 16 + (lane >> 2), kc0 = (r0 >> 2) * 32 + (lane & 3) * 8;
  const int krow1 = (r1 & 3) * 16 + (lane >> 2), kc1 = (r1 >> 2) * 32 + (lane & 3) * 8;
  const f16* kgh = kg + h * D_HEAD;
  const f16* vgh = vTg + (size_t)h * D_HEAD * L_SEQ;

  #define STAGE(buf, kv0)                                                              \
    do {                                                                               \
      gload16(&kgh[(size_t)((kv0) + krow0) * D_MODEL + kc0],                           \
              &Ks[buf][(r0 >> 2) * 2048 + (r0 & 3) * 512]);                            \
      gload16(&kgh[(size_t)((kv0) + krow1) * D_MODEL + kc1],                           \
              &Ks[buf][(r1 >> 2) * 2048 + (r1 & 3) * 512]);                            \
      gload16(&vgh[(size_t)((r0 & 3) * 16 + (lane >> 2)) * L_SEQ + (kv0) + kc0],       \
              &Vs[buf][(r0 >> 2) * 2048 + (r0 & 3) * 512]);                            \
      gload16(&vgh[(size_t)((r1 & 3) * 16 + (lane >> 2)) * L_SEQ + (kv0) + kc1],       \
              &Vs[buf][(r1 >> 2) * 2048 + (r1 & 3) * 512]);                            \
    } while (0)

  STAGE(0, kvbase);
  __syncthreads();

  f32x4 zf = {0.f, 0.f, 0.f, 0.f};
  f32x4 oacc[2][4];
  #pragma unroll
  for (int sub = 0; sub < 2; ++sub)
    #pragma unroll
    for (int dg = 0; dg < 4; ++dg) oacc[sub][dg] = zf;
  float rs[2][4] = {{0.f, 0.f, 0.f, 0.f}, {0.f, 0.f, 0.f, 0.f}};

  const int qtg0 = (q0 >> 4);  // q-tile index of sub 0
  f16* myP = Ps[w];

  for (int st = 0; st < nsteps; ++st) {
    const int buf = st & 1;
    const int kv0 = kvbase + st * 64;
    if (st + 1 < nsteps) STAGE(buf ^ 1, kv0 + 64);

    // ---- S = Q @ K^T : s[sub][j], col=kv j*16+lr, row=q lg*4+r ----
    f32x4 s[2][4];
    #pragma unroll
    for (int sub = 0; sub < 2; ++sub)
      #pragma unroll
      for (int j = 0; j < 4; ++j) s[sub][j] = zf;
    #pragma unroll
    for (int j = 0; j < 4; ++j) {
      f16x8 k0 = *(const f16x8*)&Ks[buf][(j * 16 + lr) * 32 + lg * 8];
      f16x8 k1 = *(const f16x8*)&Ks[buf][2048 + (j * 16 + lr) * 32 + lg * 8];
      s[0][j] = __builtin_amdgcn_mfma_f32_16x16x32_f16(qf[0][0], k0, s[0][j], 0, 0, 0);
      s[0][j] = __builtin_amdgcn_mfma_f32_16x16x32_f16(qf[0][1], k1, s[0][j], 0, 0, 0);
      s[1][j] = __builtin_amdgcn_mfma_f32_16x16x32_f16(qf[1][0], k0, s[1][j], 0, 0, 0);
      s[1][j] = __builtin_amdgcn_mfma_f32_16x16x32_f16(qf[1][1], k1, s[1][j], 0, 0, 0);
    }

    // ---- p = exp(s/8 + bias); store to P (per-wave), accumulate rowsums ----
    #pragma unroll
    for (int sub = 0; sub < 2; ++sub) {
      const f16* bb = &bt[((size_t)(qtg0 + sub) * 256 + (kv0 >> 4)) * 256 + lr * 16 + lg * 4];
      #pragma unroll
      for (int j = 0; j < 4; ++j) {
        f16x4 bv = *(const f16x4*)&bb[j * 256];
        #pragma unroll
        for (int r = 0; r < 4; ++r) {
          float p = __expf(fmaf(s[sub][j][r], 0.125f, (float)bv[r]));
          rs[sub][r] += p;
          myP[(j >> 1) * 1280 + (sub * 16 + lg * 4 + r) * 40 + (j & 1) * 16 + lr] = (f16)p;
        }
      }
    }

    // ---- O += P @ V ----
    f16x8 pf[2][2];
    #pragma unroll
    for (int sub = 0; sub < 2; ++sub)
      #pragma unroll
      for (int kh = 0; kh < 2; ++kh)
        pf[sub][kh] = *(const f16x8*)&myP[kh * 1280 + (sub * 16 + lr) * 40 + lg * 8];
    #pragma unroll
    for (int dg = 0; dg < 4; ++dg) {
      f16x8 v0 = *(const f16x8*)&Vs[buf][(dg * 16 + lr) * 32 + lg * 8];
      f16x8 v1 = *(const f16x8*)&Vs[buf][2048 + (dg * 16 + lr) * 32 + lg * 8];
      oacc[0][dg] = __builtin_amdgcn_mfma_f32_16x16x32_f16(pf[0][0], v0, oacc[0][dg], 0, 0, 0);
      oacc[0][dg] = __builtin_amdgcn_mfma_f32_16x16x32_f16(pf[0][1], v1, oacc[0][dg], 0, 0, 0);
      oacc[1][dg] = __builtin_amdgcn_mfma_f32_16x16x32_f16(pf[1][0], v0, oacc[1][dg], 0, 0, 0);
      oacc[1][dg] = __builtin_amdgcn_mfma_f32_16x16x32_f16(pf[1][1], v1, oacc[1][dg], 0, 0, 0);
    }
    __syncthreads();
  }

  // ---- epilogue: write partial O and partial rowsums ----
  float* op = opart + (size_t)blockIdx.z * (L_SEQ * D_MODEL);
  #pragma unroll
  for (int sub = 0; sub < 2; ++sub) {
    #pragma unroll
    for (int r = 0; r < 4; ++r) {
      float v = rs[sub][r];
      v += __shfl_xor(v, 1, 64);
      v += __shfl_xor(v, 2, 64);
      v += __shfl_xor(v, 4, 64);
      v += __shfl_xor(v, 8, 64);
      rs[sub][r] = v;
    }
    const int qrow = q0 + sub * 16 + lg * 4;
    #pragma unroll
    for (int dg = 0; dg < 4; ++dg)
      #pragma unroll
      for (int r = 0; r < 4; ++r)
        op[(size_t)(qrow + r) * D_MODEL + h * D_HEAD + dg * 16 + lr] = oacc[sub][dg][r];
    if (lr == 0) {
      #pragma unroll
      for (int r = 0; r < 4; ++r)
        rspart[((size_t)blockIdx.z * 8 + h) * L_SEQ + qrow + r] = rs[sub][r];
    }
  }
  #undef STAGE
}

// ---------------- combine kv-split partials -> normalized f16 ----------------
__global__ void combine_kernel(const float* __restrict__ opart,
                               const float* __restrict__ rspart,
                               f16* __restrict__ attout)
{
  const int idx = blockIdx.x * 256 + threadIdx.x;  // 524288 total
  const int q = idx >> 7;
  const int d = (idx & 127) * 4;
  const int h = d >> 6;
  const float rsum = rspart[h * L_SEQ + q] + rspart[(8 + h) * L_SEQ + q];
  const float inv = 1.f / rsum;
  float4 a = *(const float4*)&opart[(size_t)q * D_MODEL + d];
  float4 b = *(const float4*)&opart[(size_t)(L_SEQ * D_MODEL) + (size_t)q * D_MODEL + d];
  f16x4 u;
  u[0] = (f16)((a.x + b.x) * inv);
  u[1] = (f16)((a.y + b.y) * inv);
  u[2] = (f16)((a.z + b.z) * inv);
  u[3] = (f16)((a.w + b.w) * inv);
  *(f16x4*)&attout[(size_t)q * D_MODEL + d] = u;
}

// ---------------- host ----------------
extern "C" void kernel_launch(void* const* d_in, const int* in_sizes, int n_in,
                              void* d_out, int out_size, void* d_ws, size_t ws_size,
                              hipStream_t stream)
{
  (void)in_sizes; (void)n_in; (void)out_size; (void)ws_size;

  const float* x    = (const float*)d_in[0];
  const float* sp   = (const float*)d_in[1];
  const float* wq_w = (const float*)d_in[2];
  const float* wq_b = (const float*)d_in[3];
  const float* wk_w = (const float*)d_in[4];
  const float* wk_b = (const float*)d_in[5];
  const float* wv_w = (const float*)d_in[6];
  const float* wv_b = (const float*)d_in[7];
  const float* qp_w = (const float*)d_in[8];
  const float* qp_b = (const float*)d_in[9];
  const float* kp_w = (const float*)d_in[10];
  const float* kp_b = (const float*)d_in[11];
  const float* vp_w = (const float*)d_in[12];
  const float* vp_b = (const float*)d_in[13];
  const float* out_w = (const float*)d_in[14];
  const float* out_b = (const float*)d_in[15];

  char* ws = (char*)d_ws;
  f16*   x_f    = (f16*)(ws + 0);               // 4 MiB; reused as attout later
  f16*   attout = (f16*)(ws + 0);
  f16*   wT     = (f16*)(ws + 4194304);         // 3.5 MiB
  f16*   q_f    = (f16*)(ws + 7864320);         // 4 MiB
  f16*   k_f    = (f16*)(ws + 12058624);        // 4 MiB
  f16*   vT     = (f16*)(ws + 16252928);        // 4 MiB
  f16*   tmp    = (f16*)(ws + 20447232);        // 4 MiB (dead before attn)
  float* opart  = (float*)(ws + 20447232);      // 16 MiB (overlaps tmp)
  float* rspart = (float*)(ws + 37224448);      // 256 KiB
  f16*   bias_t = (f16*)(ws + 37486592);        // 33.5 MiB

  f16* wqT  = wT + (size_t)0 * 262144;
  f16* wkT  = wT + (size_t)1 * 262144;
  f16* wvT  = wT + (size_t)2 * 262144;
  f16* qpT  = wT + (size_t)3 * 262144;
  f16* kpT  = wT + (size_t)4 * 262144;
  f16* vpT  = wT + (size_t)5 * 262144;
  f16* outT = wT + (size_t)6 * 262144;

  cvt_f16_kernel<<<2048, 256, 0, stream>>>(x, x_f, 524288);
  transpose7_kernel<<<dim3(16, 16, 7), dim3(32, 8), 0, stream>>>(
      wq_w, wk_w, wv_w, qp_w, kp_w, vp_w, out_w,
      wqT,  wkT,  wvT,  qpT,  kpT,  vpT,  outT);
  sp_bias_kernel<<<256, 512, 0, stream>>>(sp, bias_t);

  dim3 gg(32, 8);
  gemm_bt_kernel<0><<<gg, 256, 0, stream>>>(x_f, wqT, wq_b, tmp,  4096, 512, 512);
  gemm_bt_kernel<0><<<gg, 256, 0, stream>>>(tmp, qpT, qp_b, q_f,  4096, 512, 512);
  gemm_bt_kernel<0><<<gg, 256, 0, stream>>>(x_f, wkT, wk_b, tmp,  4096, 512, 512);
  gemm_bt_kernel<0><<<gg, 256, 0, stream>>>(tmp, kpT, kp_b, k_f,  4096, 512, 512);
  gemm_bt_kernel<0><<<gg, 256, 0, stream>>>(x_f, wvT, wv_b, tmp,  4096, 512, 512);
  gemm_bt_kernel<1><<<gg, 256, 0, stream>>>(tmp, vpT, vp_b, vT,   4096, 512, 512);

  attn2_kernel<<<dim3(8, 32, KVSPLIT), 256, 0, stream>>>(q_f, k_f, vT, bias_t,
                                                         opart, rspart);
  combine_kernel<<<2048, 256, 0, stream>>>(opart, rspart, attout);

  gemm_bt_kernel<2><<<gg, 256, 0, stream>>>(attout, outT, out_b, d_out, 4096, 512, 512);
}

// Round 7
// 139.746 us; speedup vs baseline: 2.3282x; 1.3326x over previous
//
#include <hip/hip_runtime.h>

typedef _Float16 f16;
typedef __fp16 fp16x2 __attribute__((ext_vector_type(2)));
typedef _Float16 f16x4 __attribute__((ext_vector_type(4)));
typedef _Float16 f16x8 __attribute__((ext_vector_type(8)));
typedef float f32x4 __attribute__((ext_vector_type(4)));
typedef float f32x16 __attribute__((ext_vector_type(16)));

#define L_SEQ 4096
#define D_MODEL 512
#define KVSPLIT 4

__device__ __forceinline__ void gload16(const void* g, void* l) {
  __builtin_amdgcn_global_load_lds((const __attribute__((address_space(1))) void*)g,
                                   (__attribute__((address_space(3))) void*)l, 16, 0, 0);
}

// ---------------- f32 -> f16 for x + 3 projection weights ----------------
__global__ void cvt4_kernel(const float* __restrict__ s0, const float* __restrict__ s1,
                            const float* __restrict__ s2, const float* __restrict__ s3,
                            f16* __restrict__ d0, f16* __restrict__ d1,
                            f16* __restrict__ d2, f16* __restrict__ d3) {
  const float* s; f16* d; int n4;
  switch (blockIdx.z) {
    case 0: s = s0; d = d0; n4 = 524288; break;
    case 1: s = s1; d = d1; n4 = 65536; break;
    case 2: s = s2; d = d2; n4 = 65536; break;
    default: s = s3; d = d3; n4 = 65536; break;
  }
  for (int i = blockIdx.x * 256 + threadIdx.x; i < n4; i += 131072) {
    float4 v = ((const float4*)s)[i];
    f16x4 o;
    o[0] = (f16)v.x; o[1] = (f16)v.y; o[2] = (f16)v.z; o[3] = (f16)v.w;
    ((f16x4*)d)[i] = o;
  }
}

// ---------------- 512x512 f32 -> transposed f16 (4 matrices) ----------------
__global__ void transpose4_kernel(
    const float* __restrict__ s0, const float* __restrict__ s1,
    const float* __restrict__ s2, const float* __restrict__ s3,
    f16* __restrict__ d0, f16* __restrict__ d1, f16* __restrict__ d2, f16* __restrict__ d3)
{
  const float* s; f16* d;
  switch (blockIdx.z) {
    case 0: s = s0; d = d0; break;
    case 1: s = s1; d = d1; break;
    case 2: s = s2; d = d2; break;
    default: s = s3; d = d3; break;
  }
  __shared__ float tl[32][33];
  const int bx = blockIdx.x * 32, by = blockIdx.y * 32;
  const int tx = threadIdx.x, ty = threadIdx.y;
  #pragma unroll
  for (int i = 0; i < 4; ++i)
    tl[ty + i * 8][tx] = s[(size_t)(by + ty + i * 8) * 512 + bx + tx];
  __syncthreads();
  #pragma unroll
  for (int i = 0; i < 4; ++i)
    d[(size_t)(bx + ty + i * 8) * 512 + by + tx] = (f16)tl[tx][ty + i * 8];
}

// ---------------- GEMM core: C[M,N] = A[M,K] @ B[K,N] (+bias), BT given [N,K] ----------
// MODE 0: f16 out; MODE 1: f16 transposed out [N,M]; MODE 2: f32 out; MODE 3: f16 out, no bias
template<int MODE, int BM>
__device__ __forceinline__ void gemm_core(
    const f16* __restrict__ A, const f16* __restrict__ BT,
    const float* __restrict__ bias, void* __restrict__ Cv,
    int M, int N, int K, f16* As, f16* Bs)
{
  constexpr int MI = BM / 32;
  const int t = threadIdx.x;
  const int w = t >> 6;
  const int bm = blockIdx.x * BM, bn = blockIdx.y * 64;
  const int m0 = (w >> 1) * (BM / 2), n0 = (w & 1) * 32;
  const int lane = t & 63, lr = lane & 15, lg = lane >> 4;

  f32x4 zf = {0.f, 0.f, 0.f, 0.f};
  f32x4 acc[MI][2];
  #pragma unroll
  for (int i = 0; i < MI; ++i)
    #pragma unroll
    for (int j = 0; j < 2; ++j)
      acc[i][j] = zf;

  const int arow = t >> 2, achk = t & 3;
  const f16* gA = A + (size_t)(bm + arow) * K + achk * 8;
  const f16* gB = BT + (size_t)(bn + arow) * K + achk * 8;
  f16* lA = As + w * 512;
  f16* lB = Bs + w * 512;

  for (int k0 = 0; k0 < K; k0 += 32) {
    gload16(gA + k0, lA);
    if constexpr (BM == 128) gload16(gA + (size_t)64 * K + k0, lA + 2048);
    gload16(gB + k0, lB);
    __syncthreads();
    f16x8 af[MI], bfv[2];
    #pragma unroll
    for (int i = 0; i < MI; ++i)
      af[i] = *(const f16x8*)&As[(m0 + i * 16 + lr) * 32 + lg * 8];
    #pragma unroll
    for (int j = 0; j < 2; ++j)
      bfv[j] = *(const f16x8*)&Bs[(n0 + j * 16 + lr) * 32 + lg * 8];
    #pragma unroll
    for (int i = 0; i < MI; ++i)
      #pragma unroll
      for (int j = 0; j < 2; ++j)
        acc[i][j] = __builtin_amdgcn_mfma_f32_16x16x32_f16(af[i], bfv[j], acc[i][j], 0, 0, 0);
    __syncthreads();
  }

  #pragma unroll
  for (int j = 0; j < 2; ++j) {
    const int gn = bn + n0 + j * 16 + lr;
    const float bv = (MODE == 3) ? 0.f : bias[gn];
    #pragma unroll
    for (int i = 0; i < MI; ++i) {
      const int gmb = bm + m0 + i * 16 + lg * 4;
      if constexpr (MODE == 0 || MODE == 3) {
        f16* C = (f16*)Cv;
        #pragma unroll
        for (int r = 0; r < 4; ++r)
          C[(size_t)(gmb + r) * N + gn] = (f16)(acc[i][j][r] + bv);
      } else if constexpr (MODE == 1) {
        f16* C = (f16*)Cv;   // [N, M]
        f16x4 u;
        u[0] = (f16)(acc[i][j][0] + bv);
        u[1] = (f16)(acc[i][j][1] + bv);
        u[2] = (f16)(acc[i][j][2] + bv);
        u[3] = (f16)(acc[i][j][3] + bv);
        *(f16x4*)&C[(size_t)gn * M + gmb] = u;
      } else {
        float* C = (float*)Cv;
        #pragma unroll
        for (int r = 0; r < 4; ++r)
          C[(size_t)(gmb + r) * N + gn] = acc[i][j][r] + bv;
      }
    }
  }
}

template<int MODE, int BM>
__global__ __launch_bounds__(256) void gemm_bt_kernel(
    const f16* __restrict__ A, const f16* __restrict__ BT,
    const float* __restrict__ bias, void* __restrict__ Cv, int M, int N, int K)
{
  __shared__ __attribute__((aligned(16))) f16 As[BM * 32];
  __shared__ __attribute__((aligned(16))) f16 Bs[64 * 32];
  gemm_core<MODE, BM>(A, BT, bias, Cv, M, N, K, As, Bs);
}

// ---------------- combined-weight GEMMs: W'T = qpT @ wq16 (3x, z-indexed) -------------
__global__ __launch_bounds__(256) void wcombine_kernel(
    const f16* __restrict__ qpT, const f16* __restrict__ kpT, const f16* __restrict__ vpT,
    const f16* __restrict__ wq16, const f16* __restrict__ wk16, const f16* __restrict__ wv16,
    f16* __restrict__ WqT, f16* __restrict__ WkT, f16* __restrict__ WvT)
{
  __shared__ __attribute__((aligned(16))) f16 As[128 * 32];
  __shared__ __attribute__((aligned(16))) f16 Bs[64 * 32];
  const f16* A; const f16* B; f16* C;
  switch (blockIdx.z) {
    case 0: A = qpT; B = wq16; C = WqT; break;
    case 1: A = kpT; B = wk16; C = WkT; break;
    default: A = vpT; B = wv16; C = WvT; break;
  }
  gemm_core<3, 128>(A, B, nullptr, C, 512, 512, 512, As, Bs);
}

// ---------------- combined biases: bc[z] = b1 @ W2 + b2 ----------------
__global__ void bcombine_kernel(
    const float* __restrict__ wq_b, const float* __restrict__ wk_b, const float* __restrict__ wv_b,
    const f16* __restrict__ qpT, const f16* __restrict__ kpT, const f16* __restrict__ vpT,
    const float* __restrict__ qp_b, const float* __restrict__ kp_b, const float* __restrict__ vp_b,
    float* __restrict__ bc)
{
  const float* b1; const f16* WT; const float* b2;
  switch (blockIdx.z) {
    case 0: b1 = wq_b; WT = qpT; b2 = qp_b; break;
    case 1: b1 = wk_b; WT = kpT; b2 = kp_b; break;
    default: b1 = wv_b; WT = vpT; b2 = vp_b; break;
  }
  const int o = blockIdx.x * 256 + threadIdx.x;
  const f16* row = WT + (size_t)o * 512;
  float s = 0.f;
  #pragma unroll 8
  for (int m = 0; m < 512; ++m)
    s += b1[m] * (float)row[m];
  bc[blockIdx.z * 512 + o] = s + b2[o];
}

// ---------------- fused QKV projection (z = 0:q, 1:k, 2:v-transposed) ----------------
__global__ __launch_bounds__(256) void gemm_qkv_kernel(
    const f16* __restrict__ x,
    const f16* __restrict__ WqT, const f16* __restrict__ WkT, const f16* __restrict__ WvT,
    const float* __restrict__ bc,
    f16* __restrict__ q_f, f16* __restrict__ k_f, f16* __restrict__ vT)
{
  __shared__ __attribute__((aligned(16))) f16 As[128 * 32];
  __shared__ __attribute__((aligned(16))) f16 Bs[64 * 32];
  const int z = blockIdx.z;
  if (z == 2)
    gemm_core<1, 128>(x, WvT, bc + 1024, vT, 4096, 512, 512, As, Bs);
  else if (z == 1)
    gemm_core<0, 128>(x, WkT, bc + 512, k_f, 4096, 512, 512, As, Bs);
  else
    gemm_core<0, 128>(x, WqT, bc, q_f, 4096, 512, 512, As, Bs);
}

// ---------------- sp bias precompute ----------------
// value = 0.5*softmax(sp,axis=-1); layout (32x32-MFMA-friendly, perfectly coalesced):
// bt[((q>>5)*128 + (kv>>5))*1024 + ((kv>>4)&1)*512 + (q&31)*16 + (kv&15)]
__global__ __launch_bounds__(512) void sp_bias_kernel(
    const float* __restrict__ spg, f16* __restrict__ bt)
{
  __shared__ __attribute__((aligned(16))) f16 ex[16 * 4104];  // row stride 8208B (16B mult)
  __shared__ float sums[16];
  const int t = threadIdx.x;

  {
    const int row = t >> 5, j = t & 31;
    const float4* srow = (const float4*)(spg + (size_t)(blockIdx.x * 16 + row) * L_SEQ);
    f16* dst = ex + row * 4104;
    float ssum = 0.f;
    #pragma unroll 4
    for (int c = 0; c < 32; ++c) {
      float4 v = srow[c * 32 + j];
      float e0 = __expf(v.x), e1 = __expf(v.y), e2 = __expf(v.z), e3 = __expf(v.w);
      ssum += (e0 + e1) + (e2 + e3);
      f16x4 u;
      u[0] = (f16)e0; u[1] = (f16)e1; u[2] = (f16)e2; u[3] = (f16)e3;
      *(f16x4*)&dst[(c * 32 + j) * 4] = u;
    }
    ssum += __shfl_xor(ssum, 1, 64);
    ssum += __shfl_xor(ssum, 2, 64);
    ssum += __shfl_xor(ssum, 4, 64);
    ssum += __shfl_xor(ssum, 8, 64);
    ssum += __shfl_xor(ssum, 16, 64);
    if (j == 0) sums[row] = ssum;
  }
  __syncthreads();

  // thread-constant: hi = t&1, qloc = (t>>1)&15, s16 = (t>>5)&1 ; kt5 = (t>>6) + 8*i
  const int hi = t & 1, qloc = (t >> 1) & 15, s16 = (t >> 5) & 1;
  const float sc = 0.5f / sums[qloc];
  const int qt5 = blockIdx.x >> 1;
  const int q31 = ((blockIdx.x & 1) << 4) + qloc;
  const f16* exr = ex + qloc * 4104 + s16 * 16 + hi * 8;
  f16* ob = bt + (size_t)qt5 * 131072 + s16 * 512 + q31 * 16 + hi * 8;
  #pragma unroll 4
  for (int i = 0; i < 16; ++i) {
    const int kt5 = (t >> 6) + i * 8;
    f16x8 v = *(const f16x8*)&exr[kt5 * 32];
    f16x8 u;
    #pragma unroll
    for (int e = 0; e < 8; ++e) u[e] = (f16)((float)v[e] * sc);
    *(f16x8*)&ob[(size_t)kt5 * 1024] = u;
  }
}

// ---------------- fused attention, 32x32x16 MFMA, in-register P ----------------
// grid (8, 32, KVSPLIT): x=head, y=q-tile(128), z=kv-split(1024 kv). 256 thr = 4 waves,
// wave owns 32 q rows. Swapped QK^T + kv-row-permuted K tiles keep P entirely in-lane.
__global__ __launch_bounds__(256, 3) void attn3_kernel(
    const f16* __restrict__ qg, const f16* __restrict__ kg,
    const f16* __restrict__ vTg, const f16* __restrict__ bt,
    f16* __restrict__ opart, float* __restrict__ rspart)
{
  __shared__ __attribute__((aligned(16))) f16 Ks[2 * 4096];
  __shared__ __attribute__((aligned(16))) f16 Vs[2 * 4096];

  const int t = threadIdx.x;
  const int w = t >> 6, lane = t & 63;
  const int l31 = lane & 31, hi = lane >> 5;
  const int h = blockIdx.x;
  const int q0w = blockIdx.y * 128 + w * 32;
  const int z = blockIdx.z;
  const int kvbase = z * (L_SEQ / KVSPLIT);
  const int NST = (L_SEQ / KVSPLIT) / 64;

  // Q B-fragments (persist): qf[dk] = Q[q0w+l31][h*64 + dk*16 + hi*8 ..+8]
  f16x8 qf[4];
  #pragma unroll
  for (int dk = 0; dk < 4; ++dk)
    qf[dk] = *(const f16x8*)&qg[(size_t)(q0w + l31) * D_MODEL + h * 64 + dk * 16 + hi * 8];

  // staging source addresses (XOR-swizzle pre-applied on global side; LDS writes linear)
  const int srow0 = t >> 3, srow1 = 32 + (t >> 3), q16 = t & 7;
  const f16* ksrc0 = kg + h * 64 + (size_t)(kvbase + srow0) * D_MODEL + ((q16 ^ (srow0 & 7)) * 8);
  const f16* ksrc1 = kg + h * 64 + (size_t)(kvbase + srow1) * D_MODEL + ((q16 ^ (srow1 & 7)) * 8);
  const f16* vsrc0 = vTg + (size_t)(h * 64 + srow0) * L_SEQ + kvbase + (q16 ^ (srow0 & 7)) * 8;
  const f16* vsrc1 = vTg + (size_t)(h * 64 + srow1) * L_SEQ + kvbase + (q16 ^ (srow1 & 7)) * 8;

  #define STAGE(buf, stp)                                                      \
    do {                                                                       \
      const size_t ko = (size_t)(stp) * 64 * D_MODEL, vo = (size_t)(stp) * 64; \
      gload16(ksrc0 + ko, &Ks[(buf) * 4096 + w * 512]);                        \
      gload16(ksrc1 + ko, &Ks[(buf) * 4096 + 2048 + w * 512]);                 \
      gload16(vsrc0 + vo, &Vs[(buf) * 4096 + w * 512]);                        \
      gload16(vsrc1 + vo, &Vs[(buf) * 4096 + 2048 + w * 512]);                 \
    } while (0)

  // K A-row permutation: swap bits 2<->3 of l31
  const int sw23 = (l31 & ~12) | ((l31 & 4) << 1) | ((l31 & 8) >> 1);
  const int r7 = sw23 & 7;
  const int krow0 = sw23 * 64, krow1 = krow0 + 2048;        // jj=0 / jj=1 row bases (f16)
  const int vr7 = l31 & 7;
  const int vrow0 = l31 * 64, vrow1 = vrow0 + 2048;         // dg=0 / dg=1

  // bias base: ((qt5*128 + kt5)*2 + s16)*512 + l31*16 + hi*8
  const f16* bb = bt + (size_t)(q0w >> 5) * 131072 + l31 * 16 + hi * 8;
  const int kvb5 = kvbase >> 5;

  f32x16 zz = {0,0,0,0,0,0,0,0,0,0,0,0,0,0,0,0};
  f32x16 o0 = zz, o1 = zz;
  float rs = 0.f;

  STAGE(0, 0);
  __syncthreads();

  for (int st = 0; st < NST; ++st) {
    const int buf = st & 1;
    if (st + 1 < NST) STAGE(buf ^ 1, st + 1);

    // bias fragments for this 64-kv step (global, L3-resident)
    const f16* bs = bb + (size_t)(kvb5 + st * 2) * 1024;
    f16x8 bl[4];   // [jj*2 + s16]
    bl[0] = *(const f16x8*)(bs);
    bl[1] = *(const f16x8*)(bs + 512);
    bl[2] = *(const f16x8*)(bs + 1024);
    bl[3] = *(const f16x8*)(bs + 1536);

    // ---- S^T = K @ Q^T (swapped), two 32-kv tiles ----
    f32x16 s0 = zz, s1 = zz;
    const f16* kb = &Ks[buf * 4096];
    #pragma unroll
    for (int dk = 0; dk < 4; ++dk) {
      const int ch = ((dk * 2 + hi) ^ r7) * 8;
      f16x8 k0 = *(const f16x8*)&kb[krow0 + ch];
      f16x8 k1 = *(const f16x8*)&kb[krow1 + ch];
      s0 = __builtin_amdgcn_mfma_f32_32x32x16_f16(k0, qf[dk], s0, 0, 0, 0);
      s1 = __builtin_amdgcn_mfma_f32_32x32x16_f16(k1, qf[dk], s1, 0, 0, 0);
    }

    // ---- p = exp(s/8 + bias); pack in-lane into PV A-fragments ----
    f16x8 pa[4];   // [kk] : kv = kk*16 + hi*8 + e
    #pragma unroll
    for (int jj = 0; jj < 2; ++jj) {
      const f32x16& s = jj ? s1 : s0;
      float pv[16];
      #pragma unroll
      for (int r = 0; r < 16; ++r) {
        const float b = (float)bl[jj * 2 + (r >> 3)][r & 7];
        pv[r] = __expf(fmaf(s[r], 0.125f, b));
        rs += pv[r];
      }
      #pragma unroll
      for (int sh = 0; sh < 2; ++sh) {
        union { fp16x2 h2[4]; f16x8 v; } u;
        u.h2[0] = __builtin_amdgcn_cvt_pkrtz(pv[sh * 8 + 0], pv[sh * 8 + 1]);
        u.h2[1] = __builtin_amdgcn_cvt_pkrtz(pv[sh * 8 + 2], pv[sh * 8 + 3]);
        u.h2[2] = __builtin_amdgcn_cvt_pkrtz(pv[sh * 8 + 4], pv[sh * 8 + 5]);
        u.h2[3] = __builtin_amdgcn_cvt_pkrtz(pv[sh * 8 + 6], pv[sh * 8 + 7]);
        pa[jj * 2 + sh] = u.v;
      }
    }

    // ---- O += P @ V ----
    const f16* vb = &Vs[buf * 4096];
    #pragma unroll
    for (int kk = 0; kk < 4; ++kk) {
      const int ch = ((kk * 2 + hi) ^ vr7) * 8;
      f16x8 v0 = *(const f16x8*)&vb[vrow0 + ch];
      f16x8 v1 = *(const f16x8*)&vb[vrow1 + ch];
      o0 = __builtin_amdgcn_mfma_f32_32x32x16_f16(pa[kk], v0, o0, 0, 0, 0);
      o1 = __builtin_amdgcn_mfma_f32_32x32x16_f16(pa[kk], v1, o1, 0, 0, 0);
    }
    __syncthreads();
  }
  #undef STAGE

  // ---- epilogue: partial O (f16) + partial rowsums ----
  rs += __shfl_xor(rs, 32, 64);
  f16* op = opart + (size_t)z * (L_SEQ * D_MODEL);
  #pragma unroll
  for (int dg = 0; dg < 2; ++dg) {
    const f32x16& o = dg ? o1 : o0;
    #pragma unroll
    for (int r = 0; r < 16; ++r) {
      const int q = q0w + (r & 3) + 8 * (r >> 2) + 4 * hi;
      op[(size_t)q * D_MODEL + h * 64 + dg * 32 + l31] = (f16)o[r];
    }
  }
  if (hi == 0)
    rspart[((size_t)z * 8 + h) * L_SEQ + q0w + l31] = rs;
}

// ---------------- combine kv-split partials -> normalized f16 ----------------
__global__ void combine4_kernel(const f16* __restrict__ opart,
                                const float* __restrict__ rspart,
                                f16* __restrict__ attout)
{
  const int idx = blockIdx.x * 256 + threadIdx.x;  // 262144
  const int q = idx >> 6;
  const int d = (idx & 63) << 3;
  const int h = d >> 6;
  float rsum = 0.f;
  #pragma unroll
  for (int zz = 0; zz < KVSPLIT; ++zz)
    rsum += rspart[((size_t)zz * 8 + h) * L_SEQ + q];
  const float inv = 1.f / rsum;
  float acc[8] = {0,0,0,0,0,0,0,0};
  #pragma unroll
  for (int zz = 0; zz < KVSPLIT; ++zz) {
    f16x8 v = *(const f16x8*)&opart[(size_t)zz * (L_SEQ * D_MODEL) + (size_t)q * D_MODEL + d];
    #pragma unroll
    for (int e = 0; e < 8; ++e) acc[e] += (float)v[e];
  }
  f16x8 u;
  #pragma unroll
  for (int e = 0; e < 8; ++e) u[e] = (f16)(acc[e] * inv);
  *(f16x8*)&attout[(size_t)q * D_MODEL + d] = u;
}

// ---------------- host ----------------
extern "C" void kernel_launch(void* const* d_in, const int* in_sizes, int n_in,
                              void* d_out, int out_size, void* d_ws, size_t ws_size,
                              hipStream_t stream)
{
  (void)in_sizes; (void)n_in; (void)out_size; (void)ws_size;

  const float* x    = (const float*)d_in[0];
  const float* sp   = (const float*)d_in[1];
  const float* wq_w = (const float*)d_in[2];
  const float* wq_b = (const float*)d_in[3];
  const float* wk_w = (const float*)d_in[4];
  const float* wk_b = (const float*)d_in[5];
  const float* wv_w = (const float*)d_in[6];
  const float* wv_b = (const float*)d_in[7];
  const float* qp_w = (const float*)d_in[8];
  const float* qp_b = (const float*)d_in[9];
  const float* kp_w = (const float*)d_in[10];
  const float* kp_b = (const float*)d_in[11];
  const float* vp_w = (const float*)d_in[12];
  const float* vp_b = (const float*)d_in[13];
  const float* out_w = (const float*)d_in[14];
  const float* out_b = (const float*)d_in[15];

  const size_t MB = 1048576;
  char* ws = (char*)d_ws;
  // phase 1 (dead before attn) -- overlapped by opart:
  f16*   x_f    = (f16*)(ws + 0);              // 4 MiB
  f16*   qpT    = (f16*)(ws + 4 * MB);
  f16*   kpT    = (f16*)(ws + 4 * MB + 524288);
  f16*   vpT    = (f16*)(ws + 5 * MB);
  f16*   wq16   = (f16*)(ws + 6 * MB);
  f16*   wk16   = (f16*)(ws + 6 * MB + 524288);
  f16*   wv16   = (f16*)(ws + 7 * MB);
  f16*   WqT    = (f16*)(ws + 7 * MB + 524288);
  f16*   WkT    = (f16*)(ws + 8 * MB);
  f16*   WvT    = (f16*)(ws + 8 * MB + 524288);
  float* bc     = (float*)(ws + 9 * MB);       // 3*512 f32
  // attn phase:
  f16*   opart  = (f16*)(ws + 0);              // 16 MiB (over phase-1 buffers)
  f16*   q_f    = (f16*)(ws + 16 * MB);        // 4 MiB; attout overlays after attn
  f16*   attout = (f16*)(ws + 16 * MB);
  f16*   k_f    = (f16*)(ws + 20 * MB);
  f16*   vT     = (f16*)(ws + 24 * MB);
  float* rspart = (float*)(ws + 28 * MB);      // 512 KiB
  f16*   bt     = (f16*)(ws + 28 * MB + 524288); // 32 MiB -> ends 60.5 MiB
  // outT lives OUTSIDE opart's range (it is consumed by the FINAL gemm, after attn3
  // has overwritten ws[0..16MB) with opart)  <-- R6 bug was outT inside that range
  f16*   outT   = (f16*)(ws + 60 * MB + 524288); // 512 KiB, ends 61 MiB

  cvt4_kernel<<<dim3(512, 1, 4), 256, 0, stream>>>(x, wq_w, wk_w, wv_w,
                                                   x_f, wq16, wk16, wv16);
  transpose4_kernel<<<dim3(16, 16, 4), dim3(32, 8), 0, stream>>>(
      qp_w, kp_w, vp_w, out_w, qpT, kpT, vpT, outT);
  sp_bias_kernel<<<256, 512, 0, stream>>>(sp, bt);

  wcombine_kernel<<<dim3(4, 8, 3), 256, 0, stream>>>(qpT, kpT, vpT,
                                                     wq16, wk16, wv16,
                                                     WqT, WkT, WvT);
  bcombine_kernel<<<dim3(2, 1, 3), 256, 0, stream>>>(wq_b, wk_b, wv_b,
                                                     qpT, kpT, vpT,
                                                     qp_b, kp_b, vp_b, bc);
  gemm_qkv_kernel<<<dim3(32, 8, 3), 256, 0, stream>>>(x_f, WqT, WkT, WvT, bc,
                                                      q_f, k_f, vT);

  attn3_kernel<<<dim3(8, 32, KVSPLIT), 256, 0, stream>>>(q_f, k_f, vT, bt,
                                                         opart, rspart);
  combine4_kernel<<<1024, 256, 0, stream>>>(opart, rspart, attout);

  gemm_bt_kernel<2, 64><<<dim3(64, 8), 256, 0, stream>>>(attout, outT, out_b,
                                                         d_out, 4096, 512, 512);
}

// Round 9
// 132.852 us; speedup vs baseline: 2.4490x; 1.0519x over previous
//
#include <hip/hip_runtime.h>

typedef _Float16 f16;
typedef __fp16 fp16x2 __attribute__((ext_vector_type(2)));
typedef _Float16 f16x4 __attribute__((ext_vector_type(4)));
typedef _Float16 f16x8 __attribute__((ext_vector_type(8)));
typedef float f32x4 __attribute__((ext_vector_type(4)));
typedef float f32x16 __attribute__((ext_vector_type(16)));

#define L_SEQ 4096
#define D_MODEL 512
#define KVSPLIT 4

__device__ __forceinline__ void gload16(const void* g, void* l) {
  __builtin_amdgcn_global_load_lds((const __attribute__((address_space(1))) void*)g,
                                   (__attribute__((address_space(3))) void*)l, 16, 0, 0);
}

// ---------------- f32 -> f16 for x + 3 projection weights ----------------
__global__ void cvt4_kernel(const float* __restrict__ s0, const float* __restrict__ s1,
                            const float* __restrict__ s2, const float* __restrict__ s3,
                            f16* __restrict__ d0, f16* __restrict__ d1,
                            f16* __restrict__ d2, f16* __restrict__ d3) {
  const float* s; f16* d; int n4;
  switch (blockIdx.z) {
    case 0: s = s0; d = d0; n4 = 524288; break;
    case 1: s = s1; d = d1; n4 = 65536; break;
    case 2: s = s2; d = d2; n4 = 65536; break;
    default: s = s3; d = d3; n4 = 65536; break;
  }
  for (int i = blockIdx.x * 256 + threadIdx.x; i < n4; i += 131072) {
    float4 v = ((const float4*)s)[i];
    f16x4 o;
    o[0] = (f16)v.x; o[1] = (f16)v.y; o[2] = (f16)v.z; o[3] = (f16)v.w;
    ((f16x4*)d)[i] = o;
  }
}

// ---------------- 512x512 f32 -> transposed f16 (4 matrices) ----------------
__global__ void transpose4_kernel(
    const float* __restrict__ s0, const float* __restrict__ s1,
    const float* __restrict__ s2, const float* __restrict__ s3,
    f16* __restrict__ d0, f16* __restrict__ d1, f16* __restrict__ d2, f16* __restrict__ d3)
{
  const float* s; f16* d;
  switch (blockIdx.z) {
    case 0: s = s0; d = d0; break;
    case 1: s = s1; d = d1; break;
    case 2: s = s2; d = d2; break;
    default: s = s3; d = d3; break;
  }
  __shared__ float tl[32][33];
  const int bx = blockIdx.x * 32, by = blockIdx.y * 32;
  const int tx = threadIdx.x, ty = threadIdx.y;
  #pragma unroll
  for (int i = 0; i < 4; ++i)
    tl[ty + i * 8][tx] = s[(size_t)(by + ty + i * 8) * 512 + bx + tx];
  __syncthreads();
  #pragma unroll
  for (int i = 0; i < 4; ++i)
    d[(size_t)(bx + ty + i * 8) * 512 + by + tx] = (f16)tl[tx][ty + i * 8];
}

// ---------------- GEMM core: C[M,N] = A[M,K] @ B[K,N] (+bias), BT given [N,K] ----------
// MODE 0: f16 out; MODE 1: f16 transposed out [N,M]; MODE 2: f32 out; MODE 3: f16 out, no bias
template<int MODE, int BM>
__device__ __forceinline__ void gemm_core(
    const f16* __restrict__ A, const f16* __restrict__ BT,
    const float* __restrict__ bias, void* __restrict__ Cv,
    int M, int N, int K, f16* As, f16* Bs)
{
  constexpr int MI = BM / 32;
  const int t = threadIdx.x;
  const int w = t >> 6;
  const int bm = blockIdx.x * BM, bn = blockIdx.y * 64;
  const int m0 = (w >> 1) * (BM / 2), n0 = (w & 1) * 32;
  const int lane = t & 63, lr = lane & 15, lg = lane >> 4;

  f32x4 zf = {0.f, 0.f, 0.f, 0.f};
  f32x4 acc[MI][2];
  #pragma unroll
  for (int i = 0; i < MI; ++i)
    #pragma unroll
    for (int j = 0; j < 2; ++j)
      acc[i][j] = zf;

  const int arow = t >> 2, achk = t & 3;
  const f16* gA = A + (size_t)(bm + arow) * K + achk * 8;
  const f16* gB = BT + (size_t)(bn + arow) * K + achk * 8;
  f16* lA = As + w * 512;
  f16* lB = Bs + w * 512;

  for (int k0 = 0; k0 < K; k0 += 32) {
    gload16(gA + k0, lA);
    if constexpr (BM == 128) gload16(gA + (size_t)64 * K + k0, lA + 2048);
    gload16(gB + k0, lB);
    __syncthreads();
    f16x8 af[MI], bfv[2];
    #pragma unroll
    for (int i = 0; i < MI; ++i)
      af[i] = *(const f16x8*)&As[(m0 + i * 16 + lr) * 32 + lg * 8];
    #pragma unroll
    for (int j = 0; j < 2; ++j)
      bfv[j] = *(const f16x8*)&Bs[(n0 + j * 16 + lr) * 32 + lg * 8];
    #pragma unroll
    for (int i = 0; i < MI; ++i)
      #pragma unroll
      for (int j = 0; j < 2; ++j)
        acc[i][j] = __builtin_amdgcn_mfma_f32_16x16x32_f16(af[i], bfv[j], acc[i][j], 0, 0, 0);
    __syncthreads();
  }

  #pragma unroll
  for (int j = 0; j < 2; ++j) {
    const int gn = bn + n0 + j * 16 + lr;
    const float bv = (MODE == 3) ? 0.f : bias[gn];
    #pragma unroll
    for (int i = 0; i < MI; ++i) {
      const int gmb = bm + m0 + i * 16 + lg * 4;
      if constexpr (MODE == 0 || MODE == 3) {
        f16* C = (f16*)Cv;
        #pragma unroll
        for (int r = 0; r < 4; ++r)
          C[(size_t)(gmb + r) * N + gn] = (f16)(acc[i][j][r] + bv);
      } else if constexpr (MODE == 1) {
        f16* C = (f16*)Cv;   // [N, M]
        f16x4 u;
        u[0] = (f16)(acc[i][j][0] + bv);
        u[1] = (f16)(acc[i][j][1] + bv);
        u[2] = (f16)(acc[i][j][2] + bv);
        u[3] = (f16)(acc[i][j][3] + bv);
        *(f16x4*)&C[(size_t)gn * M + gmb] = u;
      } else {
        float* C = (float*)Cv;
        #pragma unroll
        for (int r = 0; r < 4; ++r)
          C[(size_t)(gmb + r) * N + gn] = acc[i][j][r] + bv;
      }
    }
  }
}

template<int MODE, int BM>
__global__ __launch_bounds__(256) void gemm_bt_kernel(
    const f16* __restrict__ A, const f16* __restrict__ BT,
    const float* __restrict__ bias, void* __restrict__ Cv, int M, int N, int K)
{
  __shared__ __attribute__((aligned(16))) f16 As[BM * 32];
  __shared__ __attribute__((aligned(16))) f16 Bs[64 * 32];
  gemm_core<MODE, BM>(A, BT, bias, Cv, M, N, K, As, Bs);
}

// ---------------- combined-weight GEMMs: W'T = qpT @ wq16 (3x, z-indexed) -------------
__global__ __launch_bounds__(256) void wcombine_kernel(
    const f16* __restrict__ qpT, const f16* __restrict__ kpT, const f16* __restrict__ vpT,
    const f16* __restrict__ wq16, const f16* __restrict__ wk16, const f16* __restrict__ wv16,
    f16* __restrict__ WqT, f16* __restrict__ WkT, f16* __restrict__ WvT)
{
  __shared__ __attribute__((aligned(16))) f16 As[128 * 32];
  __shared__ __attribute__((aligned(16))) f16 Bs[64 * 32];
  const f16* A; const f16* B; f16* C;
  switch (blockIdx.z) {
    case 0: A = qpT; B = wq16; C = WqT; break;
    case 1: A = kpT; B = wk16; C = WkT; break;
    default: A = vpT; B = wv16; C = WvT; break;
  }
  gemm_core<3, 128>(A, B, nullptr, C, 512, 512, 512, As, Bs);
}

// ---------------- combined biases: bc[z] = b1 @ W2 + b2 ----------------
__global__ void bcombine_kernel(
    const float* __restrict__ wq_b, const float* __restrict__ wk_b, const float* __restrict__ wv_b,
    const f16* __restrict__ qpT, const f16* __restrict__ kpT, const f16* __restrict__ vpT,
    const float* __restrict__ qp_b, const float* __restrict__ kp_b, const float* __restrict__ vp_b,
    float* __restrict__ bc)
{
  const float* b1; const f16* WT; const float* b2;
  switch (blockIdx.z) {
    case 0: b1 = wq_b; WT = qpT; b2 = qp_b; break;
    case 1: b1 = wk_b; WT = kpT; b2 = kp_b; break;
    default: b1 = wv_b; WT = vpT; b2 = vp_b; break;
  }
  const int o = blockIdx.x * 256 + threadIdx.x;
  const f16* row = WT + (size_t)o * 512;
  float s = 0.f;
  #pragma unroll 8
  for (int m = 0; m < 512; ++m)
    s += b1[m] * (float)row[m];
  bc[blockIdx.z * 512 + o] = s + b2[o];
}

// ---------------- fused QKV projection (z = 0:q, 1:k, 2:v-transposed) ----------------
__global__ __launch_bounds__(256) void gemm_qkv_kernel(
    const f16* __restrict__ x,
    const f16* __restrict__ WqT, const f16* __restrict__ WkT, const f16* __restrict__ WvT,
    const float* __restrict__ bc,
    f16* __restrict__ q_f, f16* __restrict__ k_f, f16* __restrict__ vT)
{
  __shared__ __attribute__((aligned(16))) f16 As[128 * 32];
  __shared__ __attribute__((aligned(16))) f16 Bs[64 * 32];
  const int z = blockIdx.z;
  if (z == 2)
    gemm_core<1, 128>(x, WvT, bc + 1024, vT, 4096, 512, 512, As, Bs);
  else if (z == 1)
    gemm_core<0, 128>(x, WkT, bc + 512, k_f, 4096, 512, 512, As, Bs);
  else
    gemm_core<0, 128>(x, WqT, bc, q_f, 4096, 512, 512, As, Bs);
}

// ---------------- sp bias precompute ----------------
// value = log2(1 + 0.5*softmax(sp, axis=-1))   [f16; consumed as exp2 logit offset]
// layout: bt[((q>>5)*128 + (kv>>5))*1024 + ((kv>>4)&1)*512 + (q&31)*16 + (kv&15)]
__global__ __launch_bounds__(512) void sp_bias_kernel(
    const float* __restrict__ spg, f16* __restrict__ bt)
{
  __shared__ __attribute__((aligned(16))) f16 ex[16 * 4104];  // row stride 8208B (16B mult)
  __shared__ float sums[16];
  const int t = threadIdx.x;

  {
    const int row = t >> 5, j = t & 31;
    const float4* srow = (const float4*)(spg + (size_t)(blockIdx.x * 16 + row) * L_SEQ);
    f16* dst = ex + row * 4104;
    float ssum = 0.f;
    #pragma unroll 4
    for (int c = 0; c < 32; ++c) {
      float4 v = srow[c * 32 + j];
      float e0 = __expf(v.x), e1 = __expf(v.y), e2 = __expf(v.z), e3 = __expf(v.w);
      ssum += (e0 + e1) + (e2 + e3);
      f16x4 u;
      u[0] = (f16)e0; u[1] = (f16)e1; u[2] = (f16)e2; u[3] = (f16)e3;
      *(f16x4*)&dst[(c * 32 + j) * 4] = u;
    }
    ssum += __shfl_xor(ssum, 1, 64);
    ssum += __shfl_xor(ssum, 2, 64);
    ssum += __shfl_xor(ssum, 4, 64);
    ssum += __shfl_xor(ssum, 8, 64);
    ssum += __shfl_xor(ssum, 16, 64);
    if (j == 0) sums[row] = ssum;
  }
  __syncthreads();

  const int hi = t & 1, qloc = (t >> 1) & 15, s16 = (t >> 5) & 1;
  const float sc = 0.5f / sums[qloc];
  const int qt5 = blockIdx.x >> 1;
  const int q31 = ((blockIdx.x & 1) << 4) + qloc;
  const f16* exr = ex + qloc * 4104 + s16 * 16 + hi * 8;
  f16* ob = bt + (size_t)qt5 * 131072 + s16 * 512 + q31 * 16 + hi * 8;
  #pragma unroll 4
  for (int i = 0; i < 16; ++i) {
    const int kt5 = (t >> 6) + i * 8;
    f16x8 v = *(const f16x8*)&exr[kt5 * 32];
    f16x8 u;
    #pragma unroll
    for (int e = 0; e < 8; ++e)
      u[e] = (f16)__log2f(fmaf((float)v[e], sc, 1.0f));
    *(f16x8*)&ob[(size_t)kt5 * 1024] = u;
  }
}

// ---------------- fused attention, 32x32x16 MFMA, in-register P ----------------
// grid = 1024 linear blocks; decompose so all 8 heads of a (qtile,z) group share
// id%8 (same XCD -> bias slice L2-coloc). 256 thr = 4 waves; wave owns 32 q rows.
// Swapped QK^T + kv-row-permuted K tiles keep P entirely in-lane.
// p = exp2(s * 0.125*log2(e) + L), L = log2(1 + 0.5*softmax(sp)) from bt.
__global__ __launch_bounds__(256, 4) void attn3_kernel(
    const f16* __restrict__ qg, const f16* __restrict__ kg,
    const f16* __restrict__ vTg, const f16* __restrict__ bt,
    f16* __restrict__ opart, float* __restrict__ rspart)
{
  __shared__ __attribute__((aligned(16))) f16 Ks[2 * 4096];
  __shared__ __attribute__((aligned(16))) f16 Vs[2 * 4096];

  const int t = threadIdx.x;
  const int w = t >> 6, lane = t & 63;
  const int l31 = lane & 31, hi = lane >> 5;
  // XCD-coloc decomposition: b = (g%8) + 8*h + 64*(g/8); g = qt + 32*z
  const int b = blockIdx.x;
  const int h = (b >> 3) & 7;
  const int g = (b & 7) + ((b >> 6) << 3);
  const int qt = g & 31;
  const int z = g >> 5;
  const int q0w = qt * 128 + w * 32;
  const int kvbase = z * (L_SEQ / KVSPLIT);
  const int NST = (L_SEQ / KVSPLIT) / 64;

  // Q B-fragments (persist): qf[dk] = Q[q0w+l31][h*64 + dk*16 + hi*8 ..+8]
  f16x8 qf[4];
  #pragma unroll
  for (int dk = 0; dk < 4; ++dk)
    qf[dk] = *(const f16x8*)&qg[(size_t)(q0w + l31) * D_MODEL + h * 64 + dk * 16 + hi * 8];

  // staging source addresses (XOR-swizzle pre-applied on global side; LDS writes linear)
  const int srow0 = t >> 3, srow1 = 32 + (t >> 3), q16 = t & 7;
  const f16* ksrc0 = kg + h * 64 + (size_t)(kvbase + srow0) * D_MODEL + ((q16 ^ (srow0 & 7)) * 8);
  const f16* ksrc1 = kg + h * 64 + (size_t)(kvbase + srow1) * D_MODEL + ((q16 ^ (srow1 & 7)) * 8);
  const f16* vsrc0 = vTg + (size_t)(h * 64 + srow0) * L_SEQ + kvbase + (q16 ^ (srow0 & 7)) * 8;
  const f16* vsrc1 = vTg + (size_t)(h * 64 + srow1) * L_SEQ + kvbase + (q16 ^ (srow1 & 7)) * 8;

  #define STAGE(buf, stp)                                                      \
    do {                                                                       \
      const size_t ko = (size_t)(stp) * 64 * D_MODEL, vo = (size_t)(stp) * 64; \
      gload16(ksrc0 + ko, &Ks[(buf) * 4096 + w * 512]);                        \
      gload16(ksrc1 + ko, &Ks[(buf) * 4096 + 2048 + w * 512]);                 \
      gload16(vsrc0 + vo, &Vs[(buf) * 4096 + w * 512]);                        \
      gload16(vsrc1 + vo, &Vs[(buf) * 4096 + 2048 + w * 512]);                 \
    } while (0)

  // K A-row permutation: swap bits 2<->3 of l31
  const int sw23 = (l31 & ~12) | ((l31 & 4) << 1) | ((l31 & 8) >> 1);
  const int r7 = sw23 & 7;
  const int krow0 = sw23 * 64, krow1 = krow0 + 2048;        // jj=0 / jj=1 row bases (f16)
  const int vr7 = l31 & 7;
  const int vrow0 = l31 * 64, vrow1 = vrow0 + 2048;         // dg=0 / dg=1

  // bias base: ((qt5*128 + kt5)*2 + s16)*512 + l31*16 + hi*8
  const f16* bb = bt + (size_t)(q0w >> 5) * 131072 + l31 * 16 + hi * 8;
  const int kvb5 = kvbase >> 5;

  f32x16 zz = {0,0,0,0,0,0,0,0,0,0,0,0,0,0,0,0};
  f32x16 o0 = zz, o1 = zz;
  float rs = 0.f;

  STAGE(0, 0);
  __syncthreads();

  for (int st = 0; st < NST; ++st) {
    const int buf = st & 1;
    if (st + 1 < NST) STAGE(buf ^ 1, st + 1);

    // bias (log2-domain) fragments for this 64-kv step
    const f16* bs = bb + (size_t)(kvb5 + st * 2) * 1024;
    f16x8 bl[4];   // [jj*2 + s16]
    bl[0] = *(const f16x8*)(bs);
    bl[1] = *(const f16x8*)(bs + 512);
    bl[2] = *(const f16x8*)(bs + 1024);
    bl[3] = *(const f16x8*)(bs + 1536);

    // ---- S^T = K @ Q^T (swapped), two 32-kv tiles ----
    f32x16 s0 = zz, s1 = zz;
    const f16* kb = &Ks[buf * 4096];
    #pragma unroll
    for (int dk = 0; dk < 4; ++dk) {
      const int ch = ((dk * 2 + hi) ^ r7) * 8;
      f16x8 k0 = *(const f16x8*)&kb[krow0 + ch];
      f16x8 k1 = *(const f16x8*)&kb[krow1 + ch];
      s0 = __builtin_amdgcn_mfma_f32_32x32x16_f16(k0, qf[dk], s0, 0, 0, 0);
      s1 = __builtin_amdgcn_mfma_f32_32x32x16_f16(k1, qf[dk], s1, 0, 0, 0);
    }

    // ---- p = exp2(s*c + L); pack in-lane into PV A-fragments ----
    f16x8 pa[4];   // [kk] : kv = kk*16 + hi*8 + e
    #pragma unroll
    for (int jj = 0; jj < 2; ++jj) {
      const f32x16& s = jj ? s1 : s0;
      float pv[16];
      #pragma unroll
      for (int r = 0; r < 16; ++r) {
        const float lb = (float)bl[jj * 2 + (r >> 3)][r & 7];
        pv[r] = __builtin_amdgcn_exp2f(fmaf(s[r], 0.18033688f, lb));
      }
      #pragma unroll
      for (int sh = 0; sh < 2; ++sh) {
        union { fp16x2 h2[4]; f16x8 v; } u;
        u.h2[0] = __builtin_amdgcn_cvt_pkrtz(pv[sh * 8 + 0], pv[sh * 8 + 1]);
        u.h2[1] = __builtin_amdgcn_cvt_pkrtz(pv[sh * 8 + 2], pv[sh * 8 + 3]);
        u.h2[2] = __builtin_amdgcn_cvt_pkrtz(pv[sh * 8 + 4], pv[sh * 8 + 5]);
        u.h2[3] = __builtin_amdgcn_cvt_pkrtz(pv[sh * 8 + 6], pv[sh * 8 + 7]);
        pa[jj * 2 + sh] = u.v;
      }
    }

    // ---- rowsum from packed P (consistent with PV operand) ----
#if __has_builtin(__builtin_amdgcn_fdot2)
    {
      const fp16x2 one2 = {(__fp16)1.0f, (__fp16)1.0f};
      #pragma unroll
      for (int kk = 0; kk < 4; ++kk) {
        const fp16x2* hp = (const fp16x2*)&pa[kk];
        #pragma unroll
        for (int e = 0; e < 4; ++e)
          rs = __builtin_amdgcn_fdot2(hp[e], one2, rs, false);
      }
    }
#else
    #pragma unroll
    for (int kk = 0; kk < 4; ++kk)
      #pragma unroll
      for (int e = 0; e < 8; ++e)
        rs += (float)pa[kk][e];
#endif

    // ---- O += P @ V ----
    const f16* vb = &Vs[buf * 4096];
    #pragma unroll
    for (int kk = 0; kk < 4; ++kk) {
      const int ch = ((kk * 2 + hi) ^ vr7) * 8;
      f16x8 v0 = *(const f16x8*)&vb[vrow0 + ch];
      f16x8 v1 = *(const f16x8*)&vb[vrow1 + ch];
      o0 = __builtin_amdgcn_mfma_f32_32x32x16_f16(pa[kk], v0, o0, 0, 0, 0);
      o1 = __builtin_amdgcn_mfma_f32_32x32x16_f16(pa[kk], v1, o1, 0, 0, 0);
    }
    __syncthreads();
  }
  #undef STAGE

  // ---- epilogue: partial O (f16) + partial rowsums ----
  rs += __shfl_xor(rs, 32, 64);
  f16* op = opart + (size_t)z * (L_SEQ * D_MODEL);
  #pragma unroll
  for (int dg = 0; dg < 2; ++dg) {
    const f32x16& o = dg ? o1 : o0;
    #pragma unroll
    for (int r = 0; r < 16; ++r) {
      const int q = q0w + (r & 3) + 8 * (r >> 2) + 4 * hi;
      op[(size_t)q * D_MODEL + h * 64 + dg * 32 + l31] = (f16)o[r];
    }
  }
  if (hi == 0)
    rspart[((size_t)z * 8 + h) * L_SEQ + q0w + l31] = rs;
}

// ---------------- combine kv-split partials -> normalized f16 ----------------
__global__ void combine4_kernel(const f16* __restrict__ opart,
                                const float* __restrict__ rspart,
                                f16* __restrict__ attout)
{
  const int idx = blockIdx.x * 256 + threadIdx.x;  // 262144
  const int q = idx >> 6;
  const int d = (idx & 63) << 3;
  const int h = d >> 6;
  float rsum = 0.f;
  #pragma unroll
  for (int zz = 0; zz < KVSPLIT; ++zz)
    rsum += rspart[((size_t)zz * 8 + h) * L_SEQ + q];
  const float inv = 1.f / rsum;
  float acc[8] = {0,0,0,0,0,0,0,0};
  #pragma unroll
  for (int zz = 0; zz < KVSPLIT; ++zz) {
    f16x8 v = *(const f16x8*)&opart[(size_t)zz * (L_SEQ * D_MODEL) + (size_t)q * D_MODEL + d];
    #pragma unroll
    for (int e = 0; e < 8; ++e) acc[e] += (float)v[e];
  }
  f16x8 u;
  #pragma unroll
  for (int e = 0; e < 8; ++e) u[e] = (f16)(acc[e] * inv);
  *(f16x8*)&attout[(size_t)q * D_MODEL + d] = u;
}

// ---------------- host ----------------
extern "C" void kernel_launch(void* const* d_in, const int* in_sizes, int n_in,
                              void* d_out, int out_size, void* d_ws, size_t ws_size,
                              hipStream_t stream)
{
  (void)in_sizes; (void)n_in; (void)out_size; (void)ws_size;

  const float* x    = (const float*)d_in[0];
  const float* sp   = (const float*)d_in[1];
  const float* wq_w = (const float*)d_in[2];
  const float* wq_b = (const float*)d_in[3];
  const float* wk_w = (const float*)d_in[4];
  const float* wk_b = (const float*)d_in[5];
  const float* wv_w = (const float*)d_in[6];
  const float* wv_b = (const float*)d_in[7];
  const float* qp_w = (const float*)d_in[8];
  const float* qp_b = (const float*)d_in[9];
  const float* kp_w = (const float*)d_in[10];
  const float* kp_b = (const float*)d_in[11];
  const float* vp_w = (const float*)d_in[12];
  const float* vp_b = (const float*)d_in[13];
  const float* out_w = (const float*)d_in[14];
  const float* out_b = (const float*)d_in[15];

  const size_t MB = 1048576;
  char* ws = (char*)d_ws;
  // phase 1 (dead before attn) -- overlapped by opart:
  f16*   x_f    = (f16*)(ws + 0);              // 4 MiB
  f16*   qpT    = (f16*)(ws + 4 * MB);
  f16*   kpT    = (f16*)(ws + 4 * MB + 524288);
  f16*   vpT    = (f16*)(ws + 5 * MB);
  f16*   wq16   = (f16*)(ws + 6 * MB);
  f16*   wk16   = (f16*)(ws + 6 * MB + 524288);
  f16*   wv16   = (f16*)(ws + 7 * MB);
  f16*   WqT    = (f16*)(ws + 7 * MB + 524288);
  f16*   WkT    = (f16*)(ws + 8 * MB);
  f16*   WvT    = (f16*)(ws + 8 * MB + 524288);
  float* bc     = (float*)(ws + 9 * MB);       // 3*512 f32
  // attn phase:
  f16*   opart  = (f16*)(ws + 0);              // 16 MiB (over phase-1 buffers)
  f16*   q_f    = (f16*)(ws + 16 * MB);        // 4 MiB; attout overlays after attn
  f16*   attout = (f16*)(ws + 16 * MB);
  f16*   k_f    = (f16*)(ws + 20 * MB);
  f16*   vT     = (f16*)(ws + 24 * MB);
  float* rspart = (float*)(ws + 28 * MB);      // 512 KiB
  f16*   bt     = (f16*)(ws + 28 * MB + 524288); // 32 MiB -> ends 60.5 MiB
  // outT lives OUTSIDE opart's range (consumed by the FINAL gemm, after attn3
  // has overwritten ws[0..16MB) with opart)
  f16*   outT   = (f16*)(ws + 60 * MB + 524288); // 512 KiB, ends 61 MiB

  cvt4_kernel<<<dim3(512, 1, 4), 256, 0, stream>>>(x, wq_w, wk_w, wv_w,
                                                   x_f, wq16, wk16, wv16);
  transpose4_kernel<<<dim3(16, 16, 4), dim3(32, 8), 0, stream>>>(
      qp_w, kp_w, vp_w, out_w, qpT, kpT, vpT, outT);
  sp_bias_kernel<<<256, 512, 0, stream>>>(sp, bt);

  wcombine_kernel<<<dim3(4, 8, 3), 256, 0, stream>>>(qpT, kpT, vpT,
                                                     wq16, wk16, wv16,
                                                     WqT, WkT, WvT);
  bcombine_kernel<<<dim3(2, 1, 3), 256, 0, stream>>>(wq_b, wk_b, wv_b,
                                                     qpT, kpT, vpT,
                                                     qp_b, kp_b, vp_b, bc);
  gemm_qkv_kernel<<<dim3(32, 8, 3), 256, 0, stream>>>(x_f, WqT, WkT, WvT, bc,
                                                      q_f, k_f, vT);

  attn3_kernel<<<dim3(1024), 256, 0, stream>>>(q_f, k_f, vT, bt,
                                               opart, rspart);
  combine4_kernel<<<1024, 256, 0, stream>>>(opart, rspart, attout);

  gemm_bt_kernel<2, 64><<<dim3(64, 8), 256, 0, stream>>>(attout, outT, out_b,
                                                         d_out, 4096, 512, 512);
}